// Round 13
// baseline (960.746 us; speedup 1.0000x reference)
//
#include <hip/hip_runtime.h>
#include <hip/hip_bf16.h>

#define EPSF 1e-5f
#define BB 2
#define CC 3
#define HH 48
#define WW 48
#define SS 2304
#define DD 64
#define NHH 8
#define FFF 2048
#define NLL 8
#define KS 21
#define PP 441
#define NROW (BB*SS)      // 4608
#define KSPLIT 4
#define KB (SS/KSPLIT)    // 576
#define FFSPLIT 16

typedef __attribute__((ext_vector_type(8))) short s8v;
typedef __attribute__((ext_vector_type(4))) float f4v;
typedef unsigned short ushort_t;

__device__ __forceinline__ ushort_t f2bf(float f) {
  unsigned u = __float_as_uint(f);
  u += 0x7FFFu + ((u >> 16) & 1u);          // round-to-nearest-even
  return (ushort_t)(u >> 16);
}
__device__ __forceinline__ float bf2f(ushort_t h) {
  return __uint_as_float(((unsigned)h) << 16);
}

// ---------------- conv3x3 + batchnorm + relu -> y[b,s,d] ----------------
__global__ __launch_bounds__(256) void k_conv(const float* __restrict__ x,
    const float* __restrict__ cw, const float* __restrict__ cb,
    const float* __restrict__ bng, const float* __restrict__ bnb,
    const float* __restrict__ bnm, const float* __restrict__ bnv,
    float* __restrict__ y)
{
  int tid = blockIdx.x * 256 + threadIdx.x;      // B*S*64 = 294912 threads
  int d = tid & 63;
  int s = (tid >> 6) % SS;
  int b = tid / (SS * 64);
  int h = s / WW, w = s % WW;
  float acc = cb[d];
  #pragma unroll
  for (int c = 0; c < 3; ++c) {
    #pragma unroll
    for (int kh = 0; kh < 3; ++kh) {
      int ih = h + kh - 1;
      if (ih < 0 || ih >= HH) continue;
      #pragma unroll
      for (int kw = 0; kw < 3; ++kw) {
        int iw = w + kw - 1;
        if (iw < 0 || iw >= WW) continue;
        acc = fmaf(x[((b*3 + c)*HH + ih)*WW + iw],
                   cw[((d*3 + c)*3 + kh)*3 + kw], acc);
      }
    }
  }
  acc = (acc - bnm[d]) * rsqrtf(bnv[d] + EPSF) * bng[d] + bnb[d];
  acc = fmaxf(acc, 0.f);
  y[(size_t)(b*SS + s)*DD + d] = acc;
}

// ---- split fp32 array into bf16 hi/lo pair (for split-bf16 MFMA) ----
__global__ __launch_bounds__(256) void k_split(const float* __restrict__ w,
    ushort_t* __restrict__ hi, ushort_t* __restrict__ lo, int n)
{
  int i = blockIdx.x * 256 + threadIdx.x;
  if (i >= n) return;
  float v = w[i];
  ushort_t h = f2bf(v);
  hi[i] = h;
  lo[i] = f2bf(v - bf2f(h));
}

// ------- 32-row-tile GEMM: out[n,j] = bias[j] + sum_k A[n,k]*W[j,k] -------
__global__ __launch_bounds__(256) void k_gemm32(const float* __restrict__ A,
    const float* __restrict__ Wt, const float* __restrict__ bias,
    float* __restrict__ out, int K, int J)
{
  __shared__ float As[64][36];   // As[k][m], m in 0..31
  __shared__ float Ws[64][68];   // Ws[k][j]
  int tid = threadIdx.x;
  int m0 = blockIdx.x * 32;
  int j0 = blockIdx.y * 64;
  int tx = tid & 15, ty = tid >> 4;
  float acc[2][4] = {};
  for (int k0 = 0; k0 < K; k0 += 64) {
    #pragma unroll
    for (int i = 0; i < 8; ++i) {
      int idx = tid + i * 256;
      int m = idx >> 6, k = idx & 63;
      As[k][m] = A[(size_t)(m0 + m) * K + k0 + k];
    }
    #pragma unroll
    for (int i = 0; i < 16; ++i) {
      int idx = tid + i * 256;
      int j = idx >> 6, k = idx & 63;
      int jj = j0 + j;
      Ws[k][j] = (jj < J) ? Wt[(size_t)jj * K + k0 + k] : 0.f;
    }
    __syncthreads();
    #pragma unroll 8
    for (int k = 0; k < 64; ++k) {
      float2 af = *(const float2*)&As[k][ty * 2];
      float4 wf = *(const float4*)&Ws[k][tx * 4];
      float a[2] = {af.x, af.y};
      float w[4] = {wf.x, wf.y, wf.z, wf.w};
      #pragma unroll
      for (int i = 0; i < 2; ++i)
        #pragma unroll
        for (int j = 0; j < 4; ++j)
          acc[i][j] = fmaf(a[i], w[j], acc[i][j]);
    }
    __syncthreads();
  }
  #pragma unroll
  for (int i = 0; i < 2; ++i) {
    int m = m0 + ty * 2 + i;
    #pragma unroll
    for (int j = 0; j < 4; ++j) {
      int jj = j0 + tx * 4 + j;
      if (jj >= J) continue;
      out[(size_t)m * J + jj] = acc[i][j] + bias[jj];
    }
  }
}

// -- fused: attn split-combine + out-proj GEMM + residual + LN1 (+ y hi/lo) --
__global__ __launch_bounds__(256) void k_oproj_ln(const float* __restrict__ pl,
    const float* __restrict__ pacc,
    const float* __restrict__ Wt, const float* __restrict__ bias,
    float* __restrict__ y, const float* __restrict__ g, const float* __restrict__ bb,
    ushort_t* __restrict__ yh, ushort_t* __restrict__ yl)
{
  __shared__ float As[64][36];   // As[k][m] = o[m0+m][k]
  __shared__ float Ws[64][68];   // Ws[k][j] = Wt[j][k]
  int tid = threadIdx.x;
  int m0 = blockIdx.x * 32;
  int b = m0 / SS;               // all 32 rows share b (SS % 32 == 0)
  int tx = tid & 15, ty = tid >> 4;

  // ---- combine attention split partials -> As (one (row, head) per thread) ----
  {
    int r32 = tid & 31, hh = tid >> 5;
    int qi = (m0 % SS) + r32;
    float L = 0.f, a[8] = {};
    #pragma unroll
    for (int sp = 0; sp < KSPLIT; ++sp) {
      size_t pidx = ((size_t)sp * 16 + b * 8 + hh) * SS + qi;
      L += pl[pidx];
      const float4* pa = (const float4*)(pacc + pidx * 8);
      float4 a0 = pa[0], a1 = pa[1];
      a[0] += a0.x; a[1] += a0.y; a[2] += a0.z; a[3] += a0.w;
      a[4] += a1.x; a[5] += a1.y; a[6] += a1.z; a[7] += a1.w;
    }
    float inv = 1.f / L;
    #pragma unroll
    for (int d = 0; d < 8; ++d) As[hh * 8 + d][r32] = a[d] * inv;
  }
  #pragma unroll
  for (int i = 0; i < 16; ++i) {
    int idx = tid + i * 256;
    int j = idx >> 6, k = idx & 63;
    Ws[k][j] = Wt[(size_t)j * DD + k];
  }
  __syncthreads();

  float acc[2][4] = {};
  #pragma unroll 8
  for (int k = 0; k < 64; ++k) {
    float2 af = *(const float2*)&As[k][ty * 2];
    float4 wf = *(const float4*)&Ws[k][tx * 4];
    float a[2] = {af.x, af.y};
    float w[4] = {wf.x, wf.y, wf.z, wf.w};
    #pragma unroll
    for (int i = 0; i < 2; ++i)
      #pragma unroll
      for (int j = 0; j < 4; ++j)
        acc[i][j] = fmaf(a[i], w[j], acc[i][j]);
  }
  float4 gv = *(const float4*)&g[tx * 4];
  float4 bv = *(const float4*)&bb[tx * 4];
  float4 biv = *(const float4*)&bias[tx * 4];
  float gg[4] = {gv.x, gv.y, gv.z, gv.w};
  float bbv[4] = {bv.x, bv.y, bv.z, bv.w};
  float bi[4] = {biv.x, biv.y, biv.z, biv.w};
  #pragma unroll
  for (int i = 0; i < 2; ++i) {
    int m = m0 + ty * 2 + i;
    float4 yv = *(const float4*)&y[(size_t)m * DD + tx * 4];
    float yr[4] = {yv.x, yv.y, yv.z, yv.w};
    float z[4], s = 0.f, ss = 0.f;
    #pragma unroll
    for (int j = 0; j < 4; ++j) {
      float v = acc[i][j] + bi[j] + yr[j];
      z[j] = v; s += v; ss = fmaf(v, v, ss);
    }
    #pragma unroll
    for (int off = 1; off < 16; off <<= 1) {
      s  += __shfl_xor(s, off);
      ss += __shfl_xor(ss, off);
    }
    float mean = s * 0.015625f;
    float var = ss * 0.015625f - mean * mean;
    float inv = rsqrtf(var + EPSF);
    float ov[4];
    #pragma unroll
    for (int j = 0; j < 4; ++j)
      ov[j] = (z[j] - mean) * inv * gg[j] + bbv[j];
    *(float4*)&y[(size_t)m * DD + tx * 4] = make_float4(ov[0], ov[1], ov[2], ov[3]);
    size_t yb = (size_t)m * DD + tx * 4;
    #pragma unroll
    for (int j = 0; j < 4; ++j) {
      ushort_t h = f2bf(ov[j]);
      yh[yb + j] = h;
      yl[yb + j] = f2bf(ov[j] - bf2f(h));
    }
  }
}

// ---- fused FF via split-bf16 MFMA: pff[split] = relu(y@W1^T+b1)@W2^T ----
// grid (FFSPLIT=16, 72): linear id = split + 16*m -> XCD = split%8, so each
// XCD touches only 2 splits' weights (128 KB) -> L2-resident. 4 waves/block.
__global__ __launch_bounds__(256) void k_ff(const ushort_t* __restrict__ yh,
    const ushort_t* __restrict__ yl,
    const ushort_t* __restrict__ w1h, const ushort_t* __restrict__ w1l,
    const float* __restrict__ b1,
    const ushort_t* __restrict__ w2h, const ushort_t* __restrict__ w2l,
    float* __restrict__ pff)
{
  __shared__ float Hs[64][68];   // per-wave-private 16-row slices
  int tid = threadIdx.x;
  int w = tid >> 6, lane = tid & 63;
  int laneR = lane & 15, laneQ = lane >> 4;
  int split = blockIdx.x;
  int m0 = blockIdx.y * 64;

  size_t ybase = (size_t)(m0 + w * 16 + laneR) * DD + laneQ * 8;
  s8v a1h0 = *(const s8v*)(yh + ybase);
  s8v a1h1 = *(const s8v*)(yh + ybase + 32);
  s8v a1l0 = *(const s8v*)(yl + ybase);
  s8v a1l1 = *(const s8v*)(yl + ybase + 32);

  f4v acc2[4];
  #pragma unroll
  for (int nt = 0; nt < 4; ++nt) acc2[nt] = (f4v){0.f, 0.f, 0.f, 0.f};

  for (int c = 0; c < FFF / FFSPLIT / 64; ++c) {
    int ff0 = split * (FFF / FFSPLIT) + c * 64;
    #pragma unroll
    for (int nt = 0; nt < 4; ++nt) {
      size_t wb = (size_t)(ff0 + nt * 16 + laneR) * DD + laneQ * 8;
      s8v b0h = *(const s8v*)(w1h + wb);
      s8v b0l = *(const s8v*)(w1l + wb);
      s8v b1h_ = *(const s8v*)(w1h + wb + 32);
      s8v b1l_ = *(const s8v*)(w1l + wb + 32);
      f4v acc = (f4v){0.f, 0.f, 0.f, 0.f};
      acc = __builtin_amdgcn_mfma_f32_16x16x32_bf16(a1h0, b0h, acc, 0, 0, 0);
      acc = __builtin_amdgcn_mfma_f32_16x16x32_bf16(a1h0, b0l, acc, 0, 0, 0);
      acc = __builtin_amdgcn_mfma_f32_16x16x32_bf16(a1l0, b0h, acc, 0, 0, 0);
      acc = __builtin_amdgcn_mfma_f32_16x16x32_bf16(a1h1, b1h_, acc, 0, 0, 0);
      acc = __builtin_amdgcn_mfma_f32_16x16x32_bf16(a1h1, b1l_, acc, 0, 0, 0);
      acc = __builtin_amdgcn_mfma_f32_16x16x32_bf16(a1l1, b1h_, acc, 0, 0, 0);
      float bj = b1[ff0 + nt * 16 + laneR];
      #pragma unroll
      for (int r = 0; r < 4; ++r)
        Hs[w * 16 + laneQ * 4 + r][nt * 16 + laneR] = fmaxf(acc[r] + bj, 0.f);
    }
    s8v a2h[2], a2l[2];
    #pragma unroll
    for (int t = 0; t < 2; ++t) {
      const float* hp = &Hs[w * 16 + laneR][t * 32 + laneQ * 8];
      float4 h0 = *(const float4*)hp;
      float4 h1 = *(const float4*)(hp + 4);
      float tv[8] = {h0.x, h0.y, h0.z, h0.w, h1.x, h1.y, h1.z, h1.w};
      #pragma unroll
      for (int j = 0; j < 8; ++j) {
        ushort_t hb = f2bf(tv[j]);
        a2h[t][j] = (short)hb;
        a2l[t][j] = (short)f2bf(tv[j] - bf2f(hb));
      }
    }
    #pragma unroll
    for (int nt = 0; nt < 4; ++nt) {
      size_t wb = (size_t)(nt * 16 + laneR) * FFF + ff0 + laneQ * 8;
      s8v b0h = *(const s8v*)(w2h + wb);
      s8v b0l = *(const s8v*)(w2l + wb);
      s8v b1h_ = *(const s8v*)(w2h + wb + 32);
      s8v b1l_ = *(const s8v*)(w2l + wb + 32);
      acc2[nt] = __builtin_amdgcn_mfma_f32_16x16x32_bf16(a2h[0], b0h, acc2[nt], 0, 0, 0);
      acc2[nt] = __builtin_amdgcn_mfma_f32_16x16x32_bf16(a2h[0], b0l, acc2[nt], 0, 0, 0);
      acc2[nt] = __builtin_amdgcn_mfma_f32_16x16x32_bf16(a2l[0], b0h, acc2[nt], 0, 0, 0);
      acc2[nt] = __builtin_amdgcn_mfma_f32_16x16x32_bf16(a2h[1], b1h_, acc2[nt], 0, 0, 0);
      acc2[nt] = __builtin_amdgcn_mfma_f32_16x16x32_bf16(a2h[1], b1l_, acc2[nt], 0, 0, 0);
      acc2[nt] = __builtin_amdgcn_mfma_f32_16x16x32_bf16(a2l[1], b1h_, acc2[nt], 0, 0, 0);
    }
  }
  #pragma unroll
  for (int nt = 0; nt < 4; ++nt) {
    #pragma unroll
    for (int r = 0; r < 4; ++r) {
      int m = m0 + w * 16 + laneQ * 4 + r;
      pff[((size_t)split * NROW + m) * DD + nt * 16 + laneR] = acc2[nt][r];
    }
  }
}

// ---- reduce FF partials + b2 + residual + LayerNorm2, one wave per row ----
__global__ __launch_bounds__(256) void k_ff_reduce(const float* __restrict__ pff,
    const float* __restrict__ b2, float* __restrict__ y,
    const float* __restrict__ g, const float* __restrict__ bb)
{
  int lane = threadIdx.x & 63;
  int row = blockIdx.x * 4 + (threadIdx.x >> 6);
  float f = b2[lane];
  #pragma unroll
  for (int sp = 0; sp < FFSPLIT; ++sp)
    f += pff[((size_t)sp * NROW + row) * DD + lane];
  size_t base = (size_t)row * DD + lane;
  float z = y[base] + f;
  float s = z;
  #pragma unroll
  for (int off = 32; off; off >>= 1) s += __shfl_xor(s, off);
  float mean = s * 0.015625f;
  float dz = z - mean;
  float sq = dz * dz;
  #pragma unroll
  for (int off = 32; off; off >>= 1) sq += __shfl_xor(sq, off);
  float var = sq * 0.015625f;
  y[base] = dz * rsqrtf(var + EPSF) * g[lane] + bb[lane];
}

// ---- MFMA flash attention (split-K): QK^T and PV on matrix cores ----
// grid (bh=16, qtile=36 x 64q, split=4 x 576k). 4 waves/block, 16 queries/wave.
__global__ __launch_bounds__(256) void k_attn(const float* __restrict__ qkv,
    float* __restrict__ pl, float* __restrict__ pacc)
{
  __shared__ ushort_t Kb[KB][8];       // bf16 K rows: Kb[key][d]
  __shared__ ushort_t Vt[8][KB + 8];   // bf16 V transposed: Vt[d][key]
  __shared__ ushort_t Ps[4][16][40];   // per-wave P tile: Ps[w][q][key], pad 40
  int bh = blockIdx.x; int b = bh >> 3; int hh = bh & 7;
  int qt = blockIdx.y, sp = blockIdx.z;
  int tid = threadIdx.x;

  for (int r = tid; r < KB; r += 256) {
    const float* src = qkv + (size_t)(b * SS + sp * KB + r) * 192 + hh * 8;
    float4 k0 = *(const float4*)(src + 64);
    float4 k1 = *(const float4*)(src + 68);
    ushort_t kh[8] = {f2bf(k0.x), f2bf(k0.y), f2bf(k0.z), f2bf(k0.w),
                      f2bf(k1.x), f2bf(k1.y), f2bf(k1.z), f2bf(k1.w)};
    *(uint4*)&Kb[r][0] = *(const uint4*)kh;
    float4 v0 = *(const float4*)(src + 128);
    float4 v1 = *(const float4*)(src + 132);
    Vt[0][r] = f2bf(v0.x); Vt[1][r] = f2bf(v0.y);
    Vt[2][r] = f2bf(v0.z); Vt[3][r] = f2bf(v0.w);
    Vt[4][r] = f2bf(v1.x); Vt[5][r] = f2bf(v1.y);
    Vt[6][r] = f2bf(v1.z); Vt[7][r] = f2bf(v1.w);
  }
  __syncthreads();

  int w = tid >> 6, lane = tid & 63;
  int n = lane & 15, quad = lane >> 4;
  const float scq = 0.51006972783f;    // log2(e) / sqrt(8)
  const s8v zero8 = (s8v){0, 0, 0, 0, 0, 0, 0, 0};
  const f4v zero4 = (f4v){0.f, 0.f, 0.f, 0.f};

  s8v aq = zero8;
  if (quad == 0) {
    const float* qp = qkv + (size_t)(b * SS + qt * 64 + w * 16 + n) * 192 + hh * 8;
    float4 q0 = *(const float4*)qp;
    float4 q1 = *(const float4*)(qp + 4);
    aq[0] = (short)f2bf(q0.x * scq); aq[1] = (short)f2bf(q0.y * scq);
    aq[2] = (short)f2bf(q0.z * scq); aq[3] = (short)f2bf(q0.w * scq);
    aq[4] = (short)f2bf(q1.x * scq); aq[5] = (short)f2bf(q1.y * scq);
    aq[6] = (short)f2bf(q1.z * scq); aq[7] = (short)f2bf(q1.w * scq);
  }

  f4v accO = zero4;
  float l[4] = {0.f, 0.f, 0.f, 0.f};
  ushort_t (*P)[40] = Ps[w];

  for (int ck = 0; ck < KB; ck += 32) {
    s8v bk0 = zero8, bk1 = zero8;
    if (quad == 0) {
      bk0 = *(const s8v*)&Kb[ck + n][0];
      bk1 = *(const s8v*)&Kb[ck + 16 + n][0];
    }
    f4v c0 = __builtin_amdgcn_mfma_f32_16x16x32_bf16(aq, bk0, zero4, 0, 0, 0);
    f4v c1 = __builtin_amdgcn_mfma_f32_16x16x32_bf16(aq, bk1, zero4, 0, 0, 0);
    #pragma unroll
    for (int r = 0; r < 4; ++r) {
      float p = exp2f(c0[r]);
      l[r] += p;
      P[quad * 4 + r][n] = f2bf(p);
    }
    #pragma unroll
    for (int r = 0; r < 4; ++r) {
      float p = exp2f(c1[r]);
      l[r] += p;
      P[quad * 4 + r][16 + n] = f2bf(p);
    }
    s8v a2 = *(const s8v*)&P[n][quad * 8];
    s8v b2 = *(const s8v*)&Vt[n & 7][ck + quad * 8];
    accO = __builtin_amdgcn_mfma_f32_16x16x32_bf16(a2, b2, accO, 0, 0, 0);
  }

  #pragma unroll
  for (int r = 0; r < 4; ++r) {
    l[r] += __shfl_xor(l[r], 1);
    l[r] += __shfl_xor(l[r], 2);
    l[r] += __shfl_xor(l[r], 4);
    l[r] += __shfl_xor(l[r], 8);
  }
  int qbase = qt * 64 + w * 16 + quad * 4;
  size_t pbase = ((size_t)sp * 16 + bh) * SS + qbase;
  if (n == 0) {
    #pragma unroll
    for (int r = 0; r < 4; ++r) pl[pbase + r] = l[r];
  }
  if (n < 8) {
    #pragma unroll
    for (int r = 0; r < 4; ++r)
      pacc[(pbase + r) * 8 + n] = accO[r];
  }
}

// ---------------- softmax over 441 logits; probs fp32 in-place + fp32 kernel_out^T
__global__ __launch_bounds__(256) void k_softmax(float* __restrict__ logits,
    float* __restrict__ kout)
{
  __shared__ float red[8];
  int row = blockIdx.x;               // b*S + s
  int b = row / SS, s = row % SS;
  float* lp = logits + (size_t)row * PP;
  int t = threadIdx.x;
  float v0 = (t < PP) ? lp[t] : -1e30f;
  float v1 = (t + 256 < PP) ? lp[t + 256] : -1e30f;
  float mx = fmaxf(v0, v1);
  #pragma unroll
  for (int off = 32; off; off >>= 1) mx = fmaxf(mx, __shfl_xor(mx, off));
  if ((t & 63) == 0) red[t >> 6] = mx;
  __syncthreads();
  mx = fmaxf(fmaxf(red[0], red[1]), fmaxf(red[2], red[3]));
  float e0 = (t < PP) ? __expf(v0 - mx) : 0.f;
  float e1 = (t + 256 < PP) ? __expf(v1 - mx) : 0.f;
  float sm = e0 + e1;
  #pragma unroll
  for (int off = 32; off; off >>= 1) sm += __shfl_xor(sm, off);
  if ((t & 63) == 0) red[4 + (t >> 6)] = sm;
  __syncthreads();
  float inv = 1.f / (red[4] + red[5] + red[6] + red[7]);
  if (t < PP) {
    float p = e0 * inv;
    lp[t] = p;
    kout[(size_t)(b * PP + t) * SS + s] = p;
  }
  if (t + 256 < PP) {
    float p = e1 * inv;
    lp[t + 256] = p;
    kout[(size_t)(b * PP + t + 256) * SS + s] = p;
  }
}

// ------- final 21x21 reflect-padded gather: one wave per output pixel -------
__global__ __launch_bounds__(256) void k_gather(const float* __restrict__ x,
    const float* __restrict__ probs, float* __restrict__ out)
{
  int lane = threadIdx.x & 63;
  int pix = blockIdx.x * 4 + (threadIdx.x >> 6);  // 0..13823
  int w = pix % WW;
  int h = (pix / WW) % HH;
  int c = (pix / (WW * HH)) % CC;
  int b = pix / (WW * HH * CC);
  int s = h * WW + w;
  const float* pp = probs + (size_t)(b * SS + s) * PP;
  const float* xb = x + (size_t)(b * CC + c) * HH * WW;
  float acc = 0.f;
  for (int t = lane; t < PP; t += 64) {
    int kr = t / KS, kc = t - kr * KS;
    int ih = h + kr - 10;
    ih = (ih < 0) ? -ih : (ih > 47 ? 94 - ih : ih);
    int iw = w + kc - 10;
    iw = (iw < 0) ? -iw : (iw > 47 ? 94 - iw : iw);
    acc = fmaf(xb[ih * WW + iw], pp[t], acc);
  }
  #pragma unroll
  for (int off = 32; off; off >>= 1) acc += __shfl_xor(acc, off);
  if (lane == 0) out[pix] = acc;
}

extern "C" void kernel_launch(void* const* d_in, const int* in_sizes, int n_in,
                              void* d_out, int out_size, void* d_ws, size_t ws_size,
                              hipStream_t stream)
{
  (void)in_sizes; (void)n_in; (void)out_size; (void)ws_size;
  const float* x       = (const float*)d_in[0];
  const float* conv1_w = (const float*)d_in[1];
  const float* conv1_b = (const float*)d_in[2];
  const float* bn_g    = (const float*)d_in[3];
  const float* bn_b    = (const float*)d_in[4];
  const float* bn_m    = (const float*)d_in[5];
  const float* bn_v    = (const float*)d_in[6];
  const float* w_in    = (const float*)d_in[7];
  const float* b_in    = (const float*)d_in[8];
  const float* w_out   = (const float*)d_in[9];
  const float* b_out   = (const float*)d_in[10];
  const float* w1      = (const float*)d_in[11];
  const float* b1      = (const float*)d_in[12];
  const float* w2      = (const float*)d_in[13];
  const float* b2      = (const float*)d_in[14];
  const float* ln1g    = (const float*)d_in[15];
  const float* ln1b    = (const float*)d_in[16];
  const float* ln2g    = (const float*)d_in[17];
  const float* ln2b    = (const float*)d_in[18];
  const float* lw      = (const float*)d_in[19];
  const float* lb      = (const float*)d_in[20];

  // workspace: ~36.7 MiB
  float* y    = (float*)d_ws;        // 294912
  float* qkv  = y + 294912;          // 884736
  float* o    = qkv + 884736;        // 294912 (unused; kept for layout)
  float* sc   = o + 294912;          // union region: 4718592 floats
  float* pacc = sc;                  // attn acc partials: 4*16*2304*8 = 1179648
  float* pff  = sc;                  // FF partials: 16*4608*64 = 4718592
  float* logits = sc;                // 4608*441 = 2032128
  float* pl   = sc + 4718592;        // attn l partials: 4*16*2304 = 147456
  ushort_t* yh  = (ushort_t*)(pl + 589824);
  ushort_t* yl  = (ushort_t*)(pl + 589824 + 147456);
  ushort_t* w1h = (ushort_t*)(pl + 589824 + 294912);
  ushort_t* w1l = (ushort_t*)(pl + 589824 + 294912 + 524288);
  ushort_t* w2h = (ushort_t*)(pl + 589824 + 294912 + 1048576);
  ushort_t* w2l = (ushort_t*)(pl + 589824 + 294912 + 1572864);

  float* out0 = (float*)d_out;
  float* kout = out0 + (size_t)BB * CC * HH * WW;

  k_split<<<4096, 256, 0, stream>>>(w1, w1h, w1l, NLL * FFF * DD);
  k_split<<<4096, 256, 0, stream>>>(w2, w2h, w2l, NLL * FFF * DD);

  k_conv<<<1152, 256, 0, stream>>>(x, conv1_w, conv1_b, bn_g, bn_b, bn_m, bn_v, y);

  for (int l = 0; l < NLL; ++l) {
    k_gemm32<<<dim3(144, 3), 256, 0, stream>>>(y, w_in + (size_t)l * 192 * 64,
        b_in + l * 192, qkv, 64, 192);
    k_attn<<<dim3(16, 36, KSPLIT), 256, 0, stream>>>(qkv, pl, pacc);
    k_oproj_ln<<<144, 256, 0, stream>>>(pl, pacc, w_out + (size_t)l * 64 * 64,
        b_out + l * 64, y, ln1g + l * 64, ln1b + l * 64, yh, yl);
    k_ff<<<dim3(FFSPLIT, 72), 256, 0, stream>>>(yh, yl,
        w1h + (size_t)l * FFF * DD, w1l + (size_t)l * FFF * DD, b1 + (size_t)l * FFF,
        w2h + (size_t)l * FFF * DD, w2l + (size_t)l * FFF * DD, pff);
    k_ff_reduce<<<1152, 256, 0, stream>>>(pff, b2 + l * DD, y,
        ln2g + l * 64, ln2b + l * 64);
  }

  k_gemm32<<<dim3(144, 7), 256, 0, stream>>>(y, lw, lb, logits, 64, 441);
  k_softmax<<<NROW, 256, 0, stream>>>(logits, kout);
  k_gather<<<3456, 256, 0, stream>>>(x, logits, out0);
}

// Round 14
// 833.542 us; speedup vs baseline: 1.1526x; 1.1526x over previous
//
#include <hip/hip_runtime.h>
#include <hip/hip_bf16.h>

#define EPSF 1e-5f
#define BB 2
#define CC 3
#define HH 48
#define WW 48
#define SS 2304
#define DD 64
#define NHH 8
#define FFF 2048
#define NLL 8
#define KS 21
#define PP 441
#define NROW (BB*SS)      // 4608
#define KSPLIT 4
#define KB (SS/KSPLIT)    // 576
#define FFSPLIT 16

typedef __attribute__((ext_vector_type(8))) short s8v;
typedef __attribute__((ext_vector_type(4))) float f4v;
typedef unsigned short ushort_t;

__device__ __forceinline__ ushort_t f2bf(float f) {
  unsigned u = __float_as_uint(f);
  u += 0x7FFFu + ((u >> 16) & 1u);          // round-to-nearest-even
  return (ushort_t)(u >> 16);
}
__device__ __forceinline__ float bf2f(ushort_t h) {
  return __uint_as_float(((unsigned)h) << 16);
}

// ---------------- conv3x3 + batchnorm + relu -> y[b,s,d] ----------------
__global__ __launch_bounds__(256) void k_conv(const float* __restrict__ x,
    const float* __restrict__ cw, const float* __restrict__ cb,
    const float* __restrict__ bng, const float* __restrict__ bnb,
    const float* __restrict__ bnm, const float* __restrict__ bnv,
    float* __restrict__ y)
{
  int tid = blockIdx.x * 256 + threadIdx.x;      // B*S*64 = 294912 threads
  int d = tid & 63;
  int s = (tid >> 6) % SS;
  int b = tid / (SS * 64);
  int h = s / WW, w = s % WW;
  float acc = cb[d];
  #pragma unroll
  for (int c = 0; c < 3; ++c) {
    #pragma unroll
    for (int kh = 0; kh < 3; ++kh) {
      int ih = h + kh - 1;
      if (ih < 0 || ih >= HH) continue;
      #pragma unroll
      for (int kw = 0; kw < 3; ++kw) {
        int iw = w + kw - 1;
        if (iw < 0 || iw >= WW) continue;
        acc = fmaf(x[((b*3 + c)*HH + ih)*WW + iw],
                   cw[((d*3 + c)*3 + kh)*3 + kw], acc);
      }
    }
  }
  acc = (acc - bnm[d]) * rsqrtf(bnv[d] + EPSF) * bng[d] + bnb[d];
  acc = fmaxf(acc, 0.f);
  y[(size_t)(b*SS + s)*DD + d] = acc;
}

// ---- split fp32 array into bf16 hi/lo pair (for split-bf16 MFMA) ----
__global__ __launch_bounds__(256) void k_split(const float* __restrict__ w,
    ushort_t* __restrict__ hi, ushort_t* __restrict__ lo, int n)
{
  int i = blockIdx.x * 256 + threadIdx.x;
  if (i >= n) return;
  float v = w[i];
  ushort_t h = f2bf(v);
  hi[i] = h;
  lo[i] = f2bf(v - bf2f(h));
}

// ------- 32-row-tile GEMM: out[n,j] = bias[j] + sum_k A[n,k]*W[j,k] -------
__global__ __launch_bounds__(256) void k_gemm32(const float* __restrict__ A,
    const float* __restrict__ Wt, const float* __restrict__ bias,
    float* __restrict__ out, int K, int J)
{
  __shared__ float As[64][36];   // As[k][m], m in 0..31
  __shared__ float Ws[64][68];   // Ws[k][j]
  int tid = threadIdx.x;
  int m0 = blockIdx.x * 32;
  int j0 = blockIdx.y * 64;
  int tx = tid & 15, ty = tid >> 4;
  float acc[2][4] = {};
  for (int k0 = 0; k0 < K; k0 += 64) {
    #pragma unroll
    for (int i = 0; i < 8; ++i) {
      int idx = tid + i * 256;
      int m = idx >> 6, k = idx & 63;
      As[k][m] = A[(size_t)(m0 + m) * K + k0 + k];
    }
    #pragma unroll
    for (int i = 0; i < 16; ++i) {
      int idx = tid + i * 256;
      int j = idx >> 6, k = idx & 63;
      int jj = j0 + j;
      Ws[k][j] = (jj < J) ? Wt[(size_t)jj * K + k0 + k] : 0.f;
    }
    __syncthreads();
    #pragma unroll 8
    for (int k = 0; k < 64; ++k) {
      float2 af = *(const float2*)&As[k][ty * 2];
      float4 wf = *(const float4*)&Ws[k][tx * 4];
      float a[2] = {af.x, af.y};
      float w[4] = {wf.x, wf.y, wf.z, wf.w};
      #pragma unroll
      for (int i = 0; i < 2; ++i)
        #pragma unroll
        for (int j = 0; j < 4; ++j)
          acc[i][j] = fmaf(a[i], w[j], acc[i][j]);
    }
    __syncthreads();
  }
  #pragma unroll
  for (int i = 0; i < 2; ++i) {
    int m = m0 + ty * 2 + i;
    #pragma unroll
    for (int j = 0; j < 4; ++j) {
      int jj = j0 + tx * 4 + j;
      if (jj >= J) continue;
      out[(size_t)m * J + jj] = acc[i][j] + bias[jj];
    }
  }
}

// -- fused: attn split-combine + out-proj GEMM + residual + LN1 (+ y hi/lo) --
__global__ __launch_bounds__(256) void k_oproj_ln(const float* __restrict__ pl,
    const float* __restrict__ pacc,
    const float* __restrict__ Wt, const float* __restrict__ bias,
    float* __restrict__ y, const float* __restrict__ g, const float* __restrict__ bb,
    ushort_t* __restrict__ yh, ushort_t* __restrict__ yl)
{
  __shared__ float As[64][36];   // As[k][m] = o[m0+m][k]
  __shared__ float Ws[64][68];   // Ws[k][j] = Wt[j][k]
  int tid = threadIdx.x;
  int m0 = blockIdx.x * 32;
  int b = m0 / SS;               // all 32 rows share b (SS % 32 == 0)
  int tx = tid & 15, ty = tid >> 4;

  // ---- combine attention split partials -> As (one (row, head) per thread) ----
  {
    int r32 = tid & 31, hh = tid >> 5;
    int qi = (m0 % SS) + r32;
    float L = 0.f, a[8] = {};
    #pragma unroll
    for (int sp = 0; sp < KSPLIT; ++sp) {
      size_t pidx = ((size_t)sp * 16 + b * 8 + hh) * SS + qi;
      L += pl[pidx];
      const float4* pa = (const float4*)(pacc + pidx * 8);
      float4 a0 = pa[0], a1 = pa[1];
      a[0] += a0.x; a[1] += a0.y; a[2] += a0.z; a[3] += a0.w;
      a[4] += a1.x; a[5] += a1.y; a[6] += a1.z; a[7] += a1.w;
    }
    float inv = 1.f / L;
    #pragma unroll
    for (int d = 0; d < 8; ++d) As[hh * 8 + d][r32] = a[d] * inv;
  }
  #pragma unroll
  for (int i = 0; i < 16; ++i) {
    int idx = tid + i * 256;
    int j = idx >> 6, k = idx & 63;
    Ws[k][j] = Wt[(size_t)j * DD + k];
  }
  __syncthreads();

  float acc[2][4] = {};
  #pragma unroll 8
  for (int k = 0; k < 64; ++k) {
    float2 af = *(const float2*)&As[k][ty * 2];
    float4 wf = *(const float4*)&Ws[k][tx * 4];
    float a[2] = {af.x, af.y};
    float w[4] = {wf.x, wf.y, wf.z, wf.w};
    #pragma unroll
    for (int i = 0; i < 2; ++i)
      #pragma unroll
      for (int j = 0; j < 4; ++j)
        acc[i][j] = fmaf(a[i], w[j], acc[i][j]);
  }
  float4 gv = *(const float4*)&g[tx * 4];
  float4 bv = *(const float4*)&bb[tx * 4];
  float4 biv = *(const float4*)&bias[tx * 4];
  float gg[4] = {gv.x, gv.y, gv.z, gv.w};
  float bbv[4] = {bv.x, bv.y, bv.z, bv.w};
  float bi[4] = {biv.x, biv.y, biv.z, biv.w};
  #pragma unroll
  for (int i = 0; i < 2; ++i) {
    int m = m0 + ty * 2 + i;
    float4 yv = *(const float4*)&y[(size_t)m * DD + tx * 4];
    float yr[4] = {yv.x, yv.y, yv.z, yv.w};
    float z[4], s = 0.f, ss = 0.f;
    #pragma unroll
    for (int j = 0; j < 4; ++j) {
      float v = acc[i][j] + bi[j] + yr[j];
      z[j] = v; s += v; ss = fmaf(v, v, ss);
    }
    #pragma unroll
    for (int off = 1; off < 16; off <<= 1) {
      s  += __shfl_xor(s, off);
      ss += __shfl_xor(ss, off);
    }
    float mean = s * 0.015625f;
    float var = ss * 0.015625f - mean * mean;
    float inv = rsqrtf(var + EPSF);
    float ov[4];
    #pragma unroll
    for (int j = 0; j < 4; ++j)
      ov[j] = (z[j] - mean) * inv * gg[j] + bbv[j];
    *(float4*)&y[(size_t)m * DD + tx * 4] = make_float4(ov[0], ov[1], ov[2], ov[3]);
    size_t yb = (size_t)m * DD + tx * 4;
    #pragma unroll
    for (int j = 0; j < 4; ++j) {
      ushort_t h = f2bf(ov[j]);
      yh[yb + j] = h;
      yl[yb + j] = f2bf(ov[j] - bf2f(h));
    }
  }
}

// ---- fused FF via split-bf16 MFMA, zero-redundancy loads ----
// grid (FFSPLIT=16, 72); 4 waves/block. gemm1: wave w owns ff-slice [16w,16w+16)
// for ALL 64 rows (4 w1 frag loads/chunk). H shared in LDS. gemm2: wave w owns
// j-slice [16w,16w+16) for all 4 m-tiles (4 w2 frag loads/chunk). y fragments
// (all 4 m-tiles) loaded once and reused across chunks.
__global__ __launch_bounds__(256) void k_ff(const ushort_t* __restrict__ yh,
    const ushort_t* __restrict__ yl,
    const ushort_t* __restrict__ w1h, const ushort_t* __restrict__ w1l,
    const float* __restrict__ b1,
    const ushort_t* __restrict__ w2h, const ushort_t* __restrict__ w2l,
    float* __restrict__ pff)
{
  __shared__ float Hs[64][68];   // H[m][ff], shared across waves
  int tid = threadIdx.x;
  int w = tid >> 6, lane = tid & 63;
  int laneR = lane & 15, laneQ = lane >> 4;
  int split = blockIdx.x;
  int m0 = blockIdx.y * 64;

  // A1 fragments for all 4 m-tiles, loaded once
  s8v a1h[4][2], a1l[4][2];
  #pragma unroll
  for (int t = 0; t < 4; ++t) {
    size_t yb = (size_t)(m0 + t * 16 + laneR) * DD + laneQ * 8;
    a1h[t][0] = *(const s8v*)(yh + yb);
    a1h[t][1] = *(const s8v*)(yh + yb + 32);
    a1l[t][0] = *(const s8v*)(yl + yb);
    a1l[t][1] = *(const s8v*)(yl + yb + 32);
  }

  f4v acc2[4];
  #pragma unroll
  for (int t = 0; t < 4; ++t) acc2[t] = (f4v){0.f, 0.f, 0.f, 0.f};

  for (int c = 0; c < FFF / FFSPLIT / 64; ++c) {
    int ff0 = split * (FFF / FFSPLIT) + c * 64;
    // this wave's unique weight fragments for the chunk (issued early)
    size_t wb1 = (size_t)(ff0 + w * 16 + laneR) * DD + laneQ * 8;
    s8v b0h = *(const s8v*)(w1h + wb1);
    s8v b0l = *(const s8v*)(w1l + wb1);
    s8v b1h_ = *(const s8v*)(w1h + wb1 + 32);
    s8v b1l_ = *(const s8v*)(w1l + wb1 + 32);
    size_t wb2 = (size_t)(w * 16 + laneR) * FFF + ff0 + laneQ * 8;
    s8v c0h = *(const s8v*)(w2h + wb2);
    s8v c0l = *(const s8v*)(w2l + wb2);
    s8v c1h = *(const s8v*)(w2h + wb2 + 32);
    s8v c1l = *(const s8v*)(w2l + wb2 + 32);
    float bj = b1[ff0 + w * 16 + laneR];

    if (c) __syncthreads();   // prior chunk's gemm2 Hs reads complete
    // ---- gemm1: H[m 64][ff slice w] ----
    #pragma unroll
    for (int t = 0; t < 4; ++t) {
      f4v acc = (f4v){0.f, 0.f, 0.f, 0.f};
      acc = __builtin_amdgcn_mfma_f32_16x16x32_bf16(a1h[t][0], b0h, acc, 0, 0, 0);
      acc = __builtin_amdgcn_mfma_f32_16x16x32_bf16(a1h[t][0], b0l, acc, 0, 0, 0);
      acc = __builtin_amdgcn_mfma_f32_16x16x32_bf16(a1l[t][0], b0h, acc, 0, 0, 0);
      acc = __builtin_amdgcn_mfma_f32_16x16x32_bf16(a1h[t][1], b1h_, acc, 0, 0, 0);
      acc = __builtin_amdgcn_mfma_f32_16x16x32_bf16(a1h[t][1], b1l_, acc, 0, 0, 0);
      acc = __builtin_amdgcn_mfma_f32_16x16x32_bf16(a1l[t][1], b1h_, acc, 0, 0, 0);
      #pragma unroll
      for (int r = 0; r < 4; ++r)
        Hs[t * 16 + laneQ * 4 + r][w * 16 + laneR] = fmaxf(acc[r] + bj, 0.f);
    }
    __syncthreads();          // Hs complete
    // ---- gemm2: acc2[t] += H[m-tile t] @ w2[j slice w]^T ----
    #pragma unroll
    for (int t = 0; t < 4; ++t) {
      s8v a2h[2], a2l[2];
      #pragma unroll
      for (int half = 0; half < 2; ++half) {
        const float* hp = &Hs[t * 16 + laneR][half * 32 + laneQ * 8];
        float4 h0 = *(const float4*)hp;
        float4 h1 = *(const float4*)(hp + 4);
        float tv[8] = {h0.x, h0.y, h0.z, h0.w, h1.x, h1.y, h1.z, h1.w};
        #pragma unroll
        for (int j = 0; j < 8; ++j) {
          ushort_t hb = f2bf(tv[j]);
          a2h[half][j] = (short)hb;
          a2l[half][j] = (short)f2bf(tv[j] - bf2f(hb));
        }
      }
      acc2[t] = __builtin_amdgcn_mfma_f32_16x16x32_bf16(a2h[0], c0h, acc2[t], 0, 0, 0);
      acc2[t] = __builtin_amdgcn_mfma_f32_16x16x32_bf16(a2h[0], c0l, acc2[t], 0, 0, 0);
      acc2[t] = __builtin_amdgcn_mfma_f32_16x16x32_bf16(a2l[0], c0h, acc2[t], 0, 0, 0);
      acc2[t] = __builtin_amdgcn_mfma_f32_16x16x32_bf16(a2h[1], c1h, acc2[t], 0, 0, 0);
      acc2[t] = __builtin_amdgcn_mfma_f32_16x16x32_bf16(a2h[1], c1l, acc2[t], 0, 0, 0);
      acc2[t] = __builtin_amdgcn_mfma_f32_16x16x32_bf16(a2l[1], c1h, acc2[t], 0, 0, 0);
    }
  }
  #pragma unroll
  for (int t = 0; t < 4; ++t) {
    #pragma unroll
    for (int r = 0; r < 4; ++r) {
      int m = m0 + t * 16 + laneQ * 4 + r;
      pff[((size_t)split * NROW + m) * DD + w * 16 + laneR] = acc2[t][r];
    }
  }
}

// ---- reduce FF partials + b2 + residual + LayerNorm2, one wave per row ----
__global__ __launch_bounds__(256) void k_ff_reduce(const float* __restrict__ pff,
    const float* __restrict__ b2, float* __restrict__ y,
    const float* __restrict__ g, const float* __restrict__ bb)
{
  int lane = threadIdx.x & 63;
  int row = blockIdx.x * 4 + (threadIdx.x >> 6);
  float f = b2[lane];
  #pragma unroll
  for (int sp = 0; sp < FFSPLIT; ++sp)
    f += pff[((size_t)sp * NROW + row) * DD + lane];
  size_t base = (size_t)row * DD + lane;
  float z = y[base] + f;
  float s = z;
  #pragma unroll
  for (int off = 32; off; off >>= 1) s += __shfl_xor(s, off);
  float mean = s * 0.015625f;
  float dz = z - mean;
  float sq = dz * dz;
  #pragma unroll
  for (int off = 32; off; off >>= 1) sq += __shfl_xor(sq, off);
  float var = sq * 0.015625f;
  y[base] = dz * rsqrtf(var + EPSF) * g[lane] + bb[lane];
}

// ---- MFMA flash attention (split-K): QK^T and PV on matrix cores ----
// grid (bh=16, qtile=36 x 64q, split=4 x 576k). 4 waves/block, 16 queries/wave.
__global__ __launch_bounds__(256) void k_attn(const float* __restrict__ qkv,
    float* __restrict__ pl, float* __restrict__ pacc)
{
  __shared__ ushort_t Kb[KB][8];       // bf16 K rows: Kb[key][d]
  __shared__ ushort_t Vt[8][KB + 8];   // bf16 V transposed: Vt[d][key]
  __shared__ ushort_t Ps[4][16][40];   // per-wave P tile: Ps[w][q][key], pad 40
  int bh = blockIdx.x; int b = bh >> 3; int hh = bh & 7;
  int qt = blockIdx.y, sp = blockIdx.z;
  int tid = threadIdx.x;

  for (int r = tid; r < KB; r += 256) {
    const float* src = qkv + (size_t)(b * SS + sp * KB + r) * 192 + hh * 8;
    float4 k0 = *(const float4*)(src + 64);
    float4 k1 = *(const float4*)(src + 68);
    ushort_t kh[8] = {f2bf(k0.x), f2bf(k0.y), f2bf(k0.z), f2bf(k0.w),
                      f2bf(k1.x), f2bf(k1.y), f2bf(k1.z), f2bf(k1.w)};
    *(uint4*)&Kb[r][0] = *(const uint4*)kh;
    float4 v0 = *(const float4*)(src + 128);
    float4 v1 = *(const float4*)(src + 132);
    Vt[0][r] = f2bf(v0.x); Vt[1][r] = f2bf(v0.y);
    Vt[2][r] = f2bf(v0.z); Vt[3][r] = f2bf(v0.w);
    Vt[4][r] = f2bf(v1.x); Vt[5][r] = f2bf(v1.y);
    Vt[6][r] = f2bf(v1.z); Vt[7][r] = f2bf(v1.w);
  }
  __syncthreads();

  int w = tid >> 6, lane = tid & 63;
  int n = lane & 15, quad = lane >> 4;
  const float scq = 0.51006972783f;    // log2(e) / sqrt(8)
  const s8v zero8 = (s8v){0, 0, 0, 0, 0, 0, 0, 0};
  const f4v zero4 = (f4v){0.f, 0.f, 0.f, 0.f};

  s8v aq = zero8;
  if (quad == 0) {
    const float* qp = qkv + (size_t)(b * SS + qt * 64 + w * 16 + n) * 192 + hh * 8;
    float4 q0 = *(const float4*)qp;
    float4 q1 = *(const float4*)(qp + 4);
    aq[0] = (short)f2bf(q0.x * scq); aq[1] = (short)f2bf(q0.y * scq);
    aq[2] = (short)f2bf(q0.z * scq); aq[3] = (short)f2bf(q0.w * scq);
    aq[4] = (short)f2bf(q1.x * scq); aq[5] = (short)f2bf(q1.y * scq);
    aq[6] = (short)f2bf(q1.z * scq); aq[7] = (short)f2bf(q1.w * scq);
  }

  f4v accO = zero4;
  float l[4] = {0.f, 0.f, 0.f, 0.f};
  ushort_t (*P)[40] = Ps[w];

  for (int ck = 0; ck < KB; ck += 32) {
    s8v bk0 = zero8, bk1 = zero8;
    if (quad == 0) {
      bk0 = *(const s8v*)&Kb[ck + n][0];
      bk1 = *(const s8v*)&Kb[ck + 16 + n][0];
    }
    f4v c0 = __builtin_amdgcn_mfma_f32_16x16x32_bf16(aq, bk0, zero4, 0, 0, 0);
    f4v c1 = __builtin_amdgcn_mfma_f32_16x16x32_bf16(aq, bk1, zero4, 0, 0, 0);
    #pragma unroll
    for (int r = 0; r < 4; ++r) {
      float p = exp2f(c0[r]);
      l[r] += p;
      P[quad * 4 + r][n] = f2bf(p);
    }
    #pragma unroll
    for (int r = 0; r < 4; ++r) {
      float p = exp2f(c1[r]);
      l[r] += p;
      P[quad * 4 + r][16 + n] = f2bf(p);
    }
    s8v a2 = *(const s8v*)&P[n][quad * 8];
    s8v b2 = *(const s8v*)&Vt[n & 7][ck + quad * 8];
    accO = __builtin_amdgcn_mfma_f32_16x16x32_bf16(a2, b2, accO, 0, 0, 0);
  }

  #pragma unroll
  for (int r = 0; r < 4; ++r) {
    l[r] += __shfl_xor(l[r], 1);
    l[r] += __shfl_xor(l[r], 2);
    l[r] += __shfl_xor(l[r], 4);
    l[r] += __shfl_xor(l[r], 8);
  }
  int qbase = qt * 64 + w * 16 + quad * 4;
  size_t pbase = ((size_t)sp * 16 + bh) * SS + qbase;
  if (n == 0) {
    #pragma unroll
    for (int r = 0; r < 4; ++r) pl[pbase + r] = l[r];
  }
  if (n < 8) {
    #pragma unroll
    for (int r = 0; r < 4; ++r)
      pacc[(pbase + r) * 8 + n] = accO[r];
  }
}

// ---------------- softmax over 441 logits; probs fp32 in-place + fp32 kernel_out^T
__global__ __launch_bounds__(256) void k_softmax(float* __restrict__ logits,
    float* __restrict__ kout)
{
  __shared__ float red[8];
  int row = blockIdx.x;               // b*S + s
  int b = row / SS, s = row % SS;
  float* lp = logits + (size_t)row * PP;
  int t = threadIdx.x;
  float v0 = (t < PP) ? lp[t] : -1e30f;
  float v1 = (t + 256 < PP) ? lp[t + 256] : -1e30f;
  float mx = fmaxf(v0, v1);
  #pragma unroll
  for (int off = 32; off; off >>= 1) mx = fmaxf(mx, __shfl_xor(mx, off));
  if ((t & 63) == 0) red[t >> 6] = mx;
  __syncthreads();
  mx = fmaxf(fmaxf(red[0], red[1]), fmaxf(red[2], red[3]));
  float e0 = (t < PP) ? __expf(v0 - mx) : 0.f;
  float e1 = (t + 256 < PP) ? __expf(v1 - mx) : 0.f;
  float sm = e0 + e1;
  #pragma unroll
  for (int off = 32; off; off >>= 1) sm += __shfl_xor(sm, off);
  if ((t & 63) == 0) red[4 + (t >> 6)] = sm;
  __syncthreads();
  float inv = 1.f / (red[4] + red[5] + red[6] + red[7]);
  if (t < PP) {
    float p = e0 * inv;
    lp[t] = p;
    kout[(size_t)(b * PP + t) * SS + s] = p;
  }
  if (t + 256 < PP) {
    float p = e1 * inv;
    lp[t + 256] = p;
    kout[(size_t)(b * PP + t + 256) * SS + s] = p;
  }
}

// ------- final 21x21 reflect-padded gather: one wave per output pixel -------
__global__ __launch_bounds__(256) void k_gather(const float* __restrict__ x,
    const float* __restrict__ probs, float* __restrict__ out)
{
  int lane = threadIdx.x & 63;
  int pix = blockIdx.x * 4 + (threadIdx.x >> 6);  // 0..13823
  int w = pix % WW;
  int h = (pix / WW) % HH;
  int c = (pix / (WW * HH)) % CC;
  int b = pix / (WW * HH * CC);
  int s = h * WW + w;
  const float* pp = probs + (size_t)(b * SS + s) * PP;
  const float* xb = x + (size_t)(b * CC + c) * HH * WW;
  float acc = 0.f;
  for (int t = lane; t < PP; t += 64) {
    int kr = t / KS, kc = t - kr * KS;
    int ih = h + kr - 10;
    ih = (ih < 0) ? -ih : (ih > 47 ? 94 - ih : ih);
    int iw = w + kc - 10;
    iw = (iw < 0) ? -iw : (iw > 47 ? 94 - iw : iw);
    acc = fmaf(xb[ih * WW + iw], pp[t], acc);
  }
  #pragma unroll
  for (int off = 32; off; off >>= 1) acc += __shfl_xor(acc, off);
  if (lane == 0) out[pix] = acc;
}

extern "C" void kernel_launch(void* const* d_in, const int* in_sizes, int n_in,
                              void* d_out, int out_size, void* d_ws, size_t ws_size,
                              hipStream_t stream)
{
  (void)in_sizes; (void)n_in; (void)out_size; (void)ws_size;
  const float* x       = (const float*)d_in[0];
  const float* conv1_w = (const float*)d_in[1];
  const float* conv1_b = (const float*)d_in[2];
  const float* bn_g    = (const float*)d_in[3];
  const float* bn_b    = (const float*)d_in[4];
  const float* bn_m    = (const float*)d_in[5];
  const float* bn_v    = (const float*)d_in[6];
  const float* w_in    = (const float*)d_in[7];
  const float* b_in    = (const float*)d_in[8];
  const float* w_out   = (const float*)d_in[9];
  const float* b_out   = (const float*)d_in[10];
  const float* w1      = (const float*)d_in[11];
  const float* b1      = (const float*)d_in[12];
  const float* w2      = (const float*)d_in[13];
  const float* b2      = (const float*)d_in[14];
  const float* ln1g    = (const float*)d_in[15];
  const float* ln1b    = (const float*)d_in[16];
  const float* ln2g    = (const float*)d_in[17];
  const float* ln2b    = (const float*)d_in[18];
  const float* lw      = (const float*)d_in[19];
  const float* lb      = (const float*)d_in[20];

  // workspace: ~36.7 MiB
  float* y    = (float*)d_ws;        // 294912
  float* qkv  = y + 294912;          // 884736
  float* o    = qkv + 884736;        // 294912 (unused; kept for layout)
  float* sc   = o + 294912;          // union region: 4718592 floats
  float* pacc = sc;                  // attn acc partials: 4*16*2304*8 = 1179648
  float* pff  = sc;                  // FF partials: 16*4608*64 = 4718592
  float* logits = sc;                // 4608*441 = 2032128
  float* pl   = sc + 4718592;        // attn l partials: 4*16*2304 = 147456
  ushort_t* yh  = (ushort_t*)(pl + 589824);
  ushort_t* yl  = (ushort_t*)(pl + 589824 + 147456);
  ushort_t* w1h = (ushort_t*)(pl + 589824 + 294912);
  ushort_t* w1l = (ushort_t*)(pl + 589824 + 294912 + 524288);
  ushort_t* w2h = (ushort_t*)(pl + 589824 + 294912 + 1048576);
  ushort_t* w2l = (ushort_t*)(pl + 589824 + 294912 + 1572864);

  float* out0 = (float*)d_out;
  float* kout = out0 + (size_t)BB * CC * HH * WW;

  k_split<<<4096, 256, 0, stream>>>(w1, w1h, w1l, NLL * FFF * DD);
  k_split<<<4096, 256, 0, stream>>>(w2, w2h, w2l, NLL * FFF * DD);

  k_conv<<<1152, 256, 0, stream>>>(x, conv1_w, conv1_b, bn_g, bn_b, bn_m, bn_v, y);

  for (int l = 0; l < NLL; ++l) {
    k_gemm32<<<dim3(144, 3), 256, 0, stream>>>(y, w_in + (size_t)l * 192 * 64,
        b_in + l * 192, qkv, 64, 192);
    k_attn<<<dim3(16, 36, KSPLIT), 256, 0, stream>>>(qkv, pl, pacc);
    k_oproj_ln<<<144, 256, 0, stream>>>(pl, pacc, w_out + (size_t)l * 64 * 64,
        b_out + l * 64, y, ln1g + l * 64, ln1b + l * 64, yh, yl);
    k_ff<<<dim3(FFSPLIT, 72), 256, 0, stream>>>(yh, yl,
        w1h + (size_t)l * FFF * DD, w1l + (size_t)l * FFF * DD, b1 + (size_t)l * FFF,
        w2h + (size_t)l * FFF * DD, w2l + (size_t)l * FFF * DD, pff);
    k_ff_reduce<<<1152, 256, 0, stream>>>(pff, b2 + l * DD, y,
        ln2g + l * 64, ln2b + l * 64);
  }

  k_gemm32<<<dim3(144, 7), 256, 0, stream>>>(y, lw, lb, logits, 64, 441);
  k_softmax<<<NROW, 256, 0, stream>>>(logits, kout);
  k_gather<<<3456, 256, 0, stream>>>(x, logits, out0);
}

// Round 16
// 818.953 us; speedup vs baseline: 1.1731x; 1.0178x over previous
//
#include <hip/hip_runtime.h>
#include <hip/hip_bf16.h>

#define EPSF 1e-5f
#define BB 2
#define CC 3
#define HH 48
#define WW 48
#define SS 2304
#define DD 64
#define NHH 8
#define FFF 2048
#define NLL 8
#define KS 21
#define PP 441
#define NROW (BB*SS)      // 4608
#define KSPLIT 4
#define KB (SS/KSPLIT)    // 576
#define FFSPLIT 16

typedef __attribute__((ext_vector_type(8))) short s8v;
typedef __attribute__((ext_vector_type(4))) float f4v;
typedef unsigned short ushort_t;

__device__ __forceinline__ ushort_t f2bf(float f) {
  unsigned u = __float_as_uint(f);
  u += 0x7FFFu + ((u >> 16) & 1u);          // round-to-nearest-even
  return (ushort_t)(u >> 16);
}
__device__ __forceinline__ float bf2f(ushort_t h) {
  return __uint_as_float(((unsigned)h) << 16);
}

// ---------------- conv3x3 + batchnorm + relu -> y[b,s,d] ----------------
__global__ __launch_bounds__(256) void k_conv(const float* __restrict__ x,
    const float* __restrict__ cw, const float* __restrict__ cb,
    const float* __restrict__ bng, const float* __restrict__ bnb,
    const float* __restrict__ bnm, const float* __restrict__ bnv,
    float* __restrict__ y)
{
  int tid = blockIdx.x * 256 + threadIdx.x;      // B*S*64 = 294912 threads
  int d = tid & 63;
  int s = (tid >> 6) % SS;
  int b = tid / (SS * 64);
  int h = s / WW, w = s % WW;
  float acc = cb[d];
  #pragma unroll
  for (int c = 0; c < 3; ++c) {
    #pragma unroll
    for (int kh = 0; kh < 3; ++kh) {
      int ih = h + kh - 1;
      if (ih < 0 || ih >= HH) continue;
      #pragma unroll
      for (int kw = 0; kw < 3; ++kw) {
        int iw = w + kw - 1;
        if (iw < 0 || iw >= WW) continue;
        acc = fmaf(x[((b*3 + c)*HH + ih)*WW + iw],
                   cw[((d*3 + c)*3 + kh)*3 + kw], acc);
      }
    }
  }
  acc = (acc - bnm[d]) * rsqrtf(bnv[d] + EPSF) * bng[d] + bnb[d];
  acc = fmaxf(acc, 0.f);
  y[(size_t)(b*SS + s)*DD + d] = acc;
}

// ---- split w1 AND w2 fp32 -> bf16 hi/lo pairs in one dispatch ----
__global__ __launch_bounds__(256) void k_split2(const float* __restrict__ w1,
    const float* __restrict__ w2,
    ushort_t* __restrict__ w1h, ushort_t* __restrict__ w1l,
    ushort_t* __restrict__ w2h, ushort_t* __restrict__ w2l)
{
  const int n = NLL * FFF * DD;
  int i = blockIdx.x * 256 + threadIdx.x;
  if (i < n) {
    float v = w1[i];
    ushort_t h = f2bf(v);
    w1h[i] = h;
    w1l[i] = f2bf(v - bf2f(h));
  } else if (i < 2 * n) {
    int j = i - n;
    float v = w2[j];
    ushort_t h = f2bf(v);
    w2h[j] = h;
    w2l[j] = f2bf(v - bf2f(h));
  }
}

// --- 32-row GEMM (K=64) with optional fused FF-reduce + LN2 prologue ---
// pff!=null: As <- LN2(Ain + b2 + sum_sp pff) (bit-identical to k_ff_reduce);
// LN2 output written to ywr (DIFFERENT buffer than Ain -- no cross-block race)
// by j0==0 blocks. pff==null: As <- Ain.
__global__ __launch_bounds__(256) void k_gemm32f(const float* __restrict__ A,
    const float* __restrict__ Wt, const float* __restrict__ bias,
    float* __restrict__ out, int J,
    const float* __restrict__ pff, const float* __restrict__ b2,
    const float* __restrict__ g, const float* __restrict__ bb,
    float* __restrict__ ywr)
{
  __shared__ float As[64][36];   // As[k][m], m in 0..31
  __shared__ float Ws[64][68];   // Ws[k][j]
  int tid = threadIdx.x;
  int m0 = blockIdx.x * 32;
  int j0 = blockIdx.y * 64;
  int tx = tid & 15, ty = tid >> 4;
  #pragma unroll
  for (int i = 0; i < 16; ++i) {
    int idx = tid + i * 256;
    int j = idx >> 6, k = idx & 63;
    int jj = j0 + j;
    Ws[k][j] = (jj < J) ? Wt[(size_t)jj * DD + k] : 0.f;
  }
  if (pff) {
    int w = tid >> 6, lane = tid & 63;
    for (int rr = 0; rr < 8; ++rr) {
      int r32 = w * 8 + rr;
      int m = m0 + r32;
      float f = b2[lane];
      #pragma unroll
      for (int sp = 0; sp < FFSPLIT; ++sp)
        f += pff[((size_t)sp * NROW + m) * DD + lane];
      float z = A[(size_t)m * DD + lane] + f;
      float s = z;
      #pragma unroll
      for (int off = 32; off; off >>= 1) s += __shfl_xor(s, off);
      float mean = s * 0.015625f;
      float dz = z - mean;
      float sq = dz * dz;
      #pragma unroll
      for (int off = 32; off; off >>= 1) sq += __shfl_xor(sq, off);
      float var = sq * 0.015625f;
      float val = dz * rsqrtf(var + EPSF) * g[lane] + bb[lane];
      As[lane][r32] = val;
      if (j0 == 0) ywr[(size_t)m * DD + lane] = val;
    }
  } else {
    #pragma unroll
    for (int i = 0; i < 8; ++i) {
      int idx = tid + i * 256;
      int m = idx >> 6, k = idx & 63;
      As[k][m] = A[(size_t)(m0 + m) * DD + k];
    }
  }
  __syncthreads();
  float acc[2][4] = {};
  #pragma unroll 8
  for (int k = 0; k < 64; ++k) {
    float2 af = *(const float2*)&As[k][ty * 2];
    float4 wf = *(const float4*)&Ws[k][tx * 4];
    float a[2] = {af.x, af.y};
    float w[4] = {wf.x, wf.y, wf.z, wf.w};
    #pragma unroll
    for (int i = 0; i < 2; ++i)
      #pragma unroll
      for (int j = 0; j < 4; ++j)
        acc[i][j] = fmaf(a[i], w[j], acc[i][j]);
  }
  #pragma unroll
  for (int i = 0; i < 2; ++i) {
    int m = m0 + ty * 2 + i;
    #pragma unroll
    for (int j = 0; j < 4; ++j) {
      int jj = j0 + tx * 4 + j;
      if (jj >= J) continue;
      out[(size_t)m * J + jj] = acc[i][j] + bias[jj];
    }
  }
}

// -- fused: attn split-combine + out-proj GEMM + residual + LN1 (+ y hi/lo) --
// y is read-modify-written in place: each block owns its 32 rows exclusively.
__global__ __launch_bounds__(256) void k_oproj_ln(const float* __restrict__ pl,
    const float* __restrict__ pacc,
    const float* __restrict__ Wt, const float* __restrict__ bias,
    float* __restrict__ y, const float* __restrict__ g, const float* __restrict__ bb,
    ushort_t* __restrict__ yh, ushort_t* __restrict__ yl)
{
  __shared__ float As[64][36];   // As[k][m] = o[m0+m][k]
  __shared__ float Ws[64][68];   // Ws[k][j] = Wt[j][k]
  int tid = threadIdx.x;
  int m0 = blockIdx.x * 32;
  int b = m0 / SS;               // all 32 rows share b (SS % 32 == 0)
  int tx = tid & 15, ty = tid >> 4;

  {
    int r32 = tid & 31, hh = tid >> 5;
    int qi = (m0 % SS) + r32;
    float L = 0.f, a[8] = {};
    #pragma unroll
    for (int sp = 0; sp < KSPLIT; ++sp) {
      size_t pidx = ((size_t)sp * 16 + b * 8 + hh) * SS + qi;
      L += pl[pidx];
      const float4* pa = (const float4*)(pacc + pidx * 8);
      float4 a0 = pa[0], a1 = pa[1];
      a[0] += a0.x; a[1] += a0.y; a[2] += a0.z; a[3] += a0.w;
      a[4] += a1.x; a[5] += a1.y; a[6] += a1.z; a[7] += a1.w;
    }
    float inv = 1.f / L;
    #pragma unroll
    for (int d = 0; d < 8; ++d) As[hh * 8 + d][r32] = a[d] * inv;
  }
  #pragma unroll
  for (int i = 0; i < 16; ++i) {
    int idx = tid + i * 256;
    int j = idx >> 6, k = idx & 63;
    Ws[k][j] = Wt[(size_t)j * DD + k];
  }
  __syncthreads();

  float acc[2][4] = {};
  #pragma unroll 8
  for (int k = 0; k < 64; ++k) {
    float2 af = *(const float2*)&As[k][ty * 2];
    float4 wf = *(const float4*)&Ws[k][tx * 4];
    float a[2] = {af.x, af.y};
    float w[4] = {wf.x, wf.y, wf.z, wf.w};
    #pragma unroll
    for (int i = 0; i < 2; ++i)
      #pragma unroll
      for (int j = 0; j < 4; ++j)
        acc[i][j] = fmaf(a[i], w[j], acc[i][j]);
  }
  float4 gv = *(const float4*)&g[tx * 4];
  float4 bv = *(const float4*)&bb[tx * 4];
  float4 biv = *(const float4*)&bias[tx * 4];
  float gg[4] = {gv.x, gv.y, gv.z, gv.w};
  float bbv[4] = {bv.x, bv.y, bv.z, bv.w};
  float bi[4] = {biv.x, biv.y, biv.z, biv.w};
  #pragma unroll
  for (int i = 0; i < 2; ++i) {
    int m = m0 + ty * 2 + i;
    float4 yv = *(const float4*)&y[(size_t)m * DD + tx * 4];
    float yr[4] = {yv.x, yv.y, yv.z, yv.w};
    float z[4], s = 0.f, ss = 0.f;
    #pragma unroll
    for (int j = 0; j < 4; ++j) {
      float v = acc[i][j] + bi[j] + yr[j];
      z[j] = v; s += v; ss = fmaf(v, v, ss);
    }
    #pragma unroll
    for (int off = 1; off < 16; off <<= 1) {
      s  += __shfl_xor(s, off);
      ss += __shfl_xor(ss, off);
    }
    float mean = s * 0.015625f;
    float var = ss * 0.015625f - mean * mean;
    float inv = rsqrtf(var + EPSF);
    float ov[4];
    #pragma unroll
    for (int j = 0; j < 4; ++j)
      ov[j] = (z[j] - mean) * inv * gg[j] + bbv[j];
    *(float4*)&y[(size_t)m * DD + tx * 4] = make_float4(ov[0], ov[1], ov[2], ov[3]);
    size_t yb = (size_t)m * DD + tx * 4;
    #pragma unroll
    for (int j = 0; j < 4; ++j) {
      ushort_t h = f2bf(ov[j]);
      yh[yb + j] = h;
      yl[yb + j] = f2bf(ov[j] - bf2f(h));
    }
  }
}

// ---- fused FF via split-bf16 MFMA, zero-redundancy loads ----
__global__ __launch_bounds__(256) void k_ff(const ushort_t* __restrict__ yh,
    const ushort_t* __restrict__ yl,
    const ushort_t* __restrict__ w1h, const ushort_t* __restrict__ w1l,
    const float* __restrict__ b1,
    const ushort_t* __restrict__ w2h, const ushort_t* __restrict__ w2l,
    float* __restrict__ pff)
{
  __shared__ float Hs[64][68];   // H[m][ff], shared across waves
  int tid = threadIdx.x;
  int w = tid >> 6, lane = tid & 63;
  int laneR = lane & 15, laneQ = lane >> 4;
  int split = blockIdx.x;
  int m0 = blockIdx.y * 64;

  s8v a1h[4][2], a1l[4][2];
  #pragma unroll
  for (int t = 0; t < 4; ++t) {
    size_t yb = (size_t)(m0 + t * 16 + laneR) * DD + laneQ * 8;
    a1h[t][0] = *(const s8v*)(yh + yb);
    a1h[t][1] = *(const s8v*)(yh + yb + 32);
    a1l[t][0] = *(const s8v*)(yl + yb);
    a1l[t][1] = *(const s8v*)(yl + yb + 32);
  }

  f4v acc2[4];
  #pragma unroll
  for (int t = 0; t < 4; ++t) acc2[t] = (f4v){0.f, 0.f, 0.f, 0.f};

  for (int c = 0; c < FFF / FFSPLIT / 64; ++c) {
    int ff0 = split * (FFF / FFSPLIT) + c * 64;
    size_t wb1 = (size_t)(ff0 + w * 16 + laneR) * DD + laneQ * 8;
    s8v b0h = *(const s8v*)(w1h + wb1);
    s8v b0l = *(const s8v*)(w1l + wb1);
    s8v b1h_ = *(const s8v*)(w1h + wb1 + 32);
    s8v b1l_ = *(const s8v*)(w1l + wb1 + 32);
    size_t wb2 = (size_t)(w * 16 + laneR) * FFF + ff0 + laneQ * 8;
    s8v c0h = *(const s8v*)(w2h + wb2);
    s8v c0l = *(const s8v*)(w2l + wb2);
    s8v c1h = *(const s8v*)(w2h + wb2 + 32);
    s8v c1l = *(const s8v*)(w2l + wb2 + 32);
    float bj = b1[ff0 + w * 16 + laneR];

    if (c) __syncthreads();
    #pragma unroll
    for (int t = 0; t < 4; ++t) {
      f4v acc = (f4v){0.f, 0.f, 0.f, 0.f};
      acc = __builtin_amdgcn_mfma_f32_16x16x32_bf16(a1h[t][0], b0h, acc, 0, 0, 0);
      acc = __builtin_amdgcn_mfma_f32_16x16x32_bf16(a1h[t][0], b0l, acc, 0, 0, 0);
      acc = __builtin_amdgcn_mfma_f32_16x16x32_bf16(a1l[t][0], b0h, acc, 0, 0, 0);
      acc = __builtin_amdgcn_mfma_f32_16x16x32_bf16(a1h[t][1], b1h_, acc, 0, 0, 0);
      acc = __builtin_amdgcn_mfma_f32_16x16x32_bf16(a1h[t][1], b1l_, acc, 0, 0, 0);
      acc = __builtin_amdgcn_mfma_f32_16x16x32_bf16(a1l[t][1], b1h_, acc, 0, 0, 0);
      #pragma unroll
      for (int r = 0; r < 4; ++r)
        Hs[t * 16 + laneQ * 4 + r][w * 16 + laneR] = fmaxf(acc[r] + bj, 0.f);
    }
    __syncthreads();
    #pragma unroll
    for (int t = 0; t < 4; ++t) {
      s8v a2h[2], a2l[2];
      #pragma unroll
      for (int half = 0; half < 2; ++half) {
        const float* hp = &Hs[t * 16 + laneR][half * 32 + laneQ * 8];
        float4 h0 = *(const float4*)hp;
        float4 h1 = *(const float4*)(hp + 4);
        float tv[8] = {h0.x, h0.y, h0.z, h0.w, h1.x, h1.y, h1.z, h1.w};
        #pragma unroll
        for (int j = 0; j < 8; ++j) {
          ushort_t hb = f2bf(tv[j]);
          a2h[half][j] = (short)hb;
          a2l[half][j] = (short)f2bf(tv[j] - bf2f(hb));
        }
      }
      acc2[t] = __builtin_amdgcn_mfma_f32_16x16x32_bf16(a2h[0], c0h, acc2[t], 0, 0, 0);
      acc2[t] = __builtin_amdgcn_mfma_f32_16x16x32_bf16(a2h[0], c0l, acc2[t], 0, 0, 0);
      acc2[t] = __builtin_amdgcn_mfma_f32_16x16x32_bf16(a2l[0], c0h, acc2[t], 0, 0, 0);
      acc2[t] = __builtin_amdgcn_mfma_f32_16x16x32_bf16(a2h[1], c1h, acc2[t], 0, 0, 0);
      acc2[t] = __builtin_amdgcn_mfma_f32_16x16x32_bf16(a2h[1], c1l, acc2[t], 0, 0, 0);
      acc2[t] = __builtin_amdgcn_mfma_f32_16x16x32_bf16(a2l[1], c1h, acc2[t], 0, 0, 0);
    }
  }
  #pragma unroll
  for (int t = 0; t < 4; ++t) {
    #pragma unroll
    for (int r = 0; r < 4; ++r) {
      int m = m0 + t * 16 + laneQ * 4 + r;
      pff[((size_t)split * NROW + m) * DD + w * 16 + laneR] = acc2[t][r];
    }
  }
}

// ---- MFMA flash attention (split-K): QK^T and PV on matrix cores ----
__global__ __launch_bounds__(256) void k_attn(const float* __restrict__ qkv,
    float* __restrict__ pl, float* __restrict__ pacc)
{
  __shared__ ushort_t Kb[KB][8];       // bf16 K rows: Kb[key][d]
  __shared__ ushort_t Vt[8][KB + 8];   // bf16 V transposed: Vt[d][key]
  __shared__ ushort_t Ps[4][16][40];   // per-wave P tile: Ps[w][q][key], pad 40
  int bh = blockIdx.x; int b = bh >> 3; int hh = bh & 7;
  int qt = blockIdx.y, sp = blockIdx.z;
  int tid = threadIdx.x;

  for (int r = tid; r < KB; r += 256) {
    const float* src = qkv + (size_t)(b * SS + sp * KB + r) * 192 + hh * 8;
    float4 k0 = *(const float4*)(src + 64);
    float4 k1 = *(const float4*)(src + 68);
    ushort_t kh[8] = {f2bf(k0.x), f2bf(k0.y), f2bf(k0.z), f2bf(k0.w),
                      f2bf(k1.x), f2bf(k1.y), f2bf(k1.z), f2bf(k1.w)};
    *(uint4*)&Kb[r][0] = *(const uint4*)kh;
    float4 v0 = *(const float4*)(src + 128);
    float4 v1 = *(const float4*)(src + 132);
    Vt[0][r] = f2bf(v0.x); Vt[1][r] = f2bf(v0.y);
    Vt[2][r] = f2bf(v0.z); Vt[3][r] = f2bf(v0.w);
    Vt[4][r] = f2bf(v1.x); Vt[5][r] = f2bf(v1.y);
    Vt[6][r] = f2bf(v1.z); Vt[7][r] = f2bf(v1.w);
  }
  __syncthreads();

  int w = tid >> 6, lane = tid & 63;
  int n = lane & 15, quad = lane >> 4;
  const float scq = 0.51006972783f;    // log2(e) / sqrt(8)
  const s8v zero8 = (s8v){0, 0, 0, 0, 0, 0, 0, 0};
  const f4v zero4 = (f4v){0.f, 0.f, 0.f, 0.f};

  s8v aq = zero8;
  if (quad == 0) {
    const float* qp = qkv + (size_t)(b * SS + qt * 64 + w * 16 + n) * 192 + hh * 8;
    float4 q0 = *(const float4*)qp;
    float4 q1 = *(const float4*)(qp + 4);
    aq[0] = (short)f2bf(q0.x * scq); aq[1] = (short)f2bf(q0.y * scq);
    aq[2] = (short)f2bf(q0.z * scq); aq[3] = (short)f2bf(q0.w * scq);
    aq[4] = (short)f2bf(q1.x * scq); aq[5] = (short)f2bf(q1.y * scq);
    aq[6] = (short)f2bf(q1.z * scq); aq[7] = (short)f2bf(q1.w * scq);
  }

  f4v accO = zero4;
  float l[4] = {0.f, 0.f, 0.f, 0.f};
  ushort_t (*P)[40] = Ps[w];

  for (int ck = 0; ck < KB; ck += 32) {
    s8v bk0 = zero8, bk1 = zero8;
    if (quad == 0) {
      bk0 = *(const s8v*)&Kb[ck + n][0];
      bk1 = *(const s8v*)&Kb[ck + 16 + n][0];
    }
    f4v c0 = __builtin_amdgcn_mfma_f32_16x16x32_bf16(aq, bk0, zero4, 0, 0, 0);
    f4v c1 = __builtin_amdgcn_mfma_f32_16x16x32_bf16(aq, bk1, zero4, 0, 0, 0);
    #pragma unroll
    for (int r = 0; r < 4; ++r) {
      float p = exp2f(c0[r]);
      l[r] += p;
      P[quad * 4 + r][n] = f2bf(p);
    }
    #pragma unroll
    for (int r = 0; r < 4; ++r) {
      float p = exp2f(c1[r]);
      l[r] += p;
      P[quad * 4 + r][16 + n] = f2bf(p);
    }
    s8v a2 = *(const s8v*)&P[n][quad * 8];
    s8v b2 = *(const s8v*)&Vt[n & 7][ck + quad * 8];
    accO = __builtin_amdgcn_mfma_f32_16x16x32_bf16(a2, b2, accO, 0, 0, 0);
  }

  #pragma unroll
  for (int r = 0; r < 4; ++r) {
    l[r] += __shfl_xor(l[r], 1);
    l[r] += __shfl_xor(l[r], 2);
    l[r] += __shfl_xor(l[r], 4);
    l[r] += __shfl_xor(l[r], 8);
  }
  int qbase = qt * 64 + w * 16 + quad * 4;
  size_t pbase = ((size_t)sp * 16 + bh) * SS + qbase;
  if (n == 0) {
    #pragma unroll
    for (int r = 0; r < 4; ++r) pl[pbase + r] = l[r];
  }
  if (n < 8) {
    #pragma unroll
    for (int r = 0; r < 4; ++r)
      pacc[(pbase + r) * 8 + n] = accO[r];
  }
}

// ---- fused: softmax over 441 logits -> kernel_out + 3-channel gather ----
__global__ __launch_bounds__(256) void k_softgather(const float* __restrict__ logits,
    const float* __restrict__ x, float* __restrict__ kout, float* __restrict__ out)
{
  __shared__ float red[8];
  __shared__ float gred[3][4];
  int row = blockIdx.x;               // b*S + s
  int b = row / SS, s = row % SS;
  int h = s / WW, w = s % WW;
  const float* lp = logits + (size_t)row * PP;
  int t = threadIdx.x;
  float v0 = (t < PP) ? lp[t] : -1e30f;
  float v1 = (t + 256 < PP) ? lp[t + 256] : -1e30f;
  float mx = fmaxf(v0, v1);
  #pragma unroll
  for (int off = 32; off; off >>= 1) mx = fmaxf(mx, __shfl_xor(mx, off));
  if ((t & 63) == 0) red[t >> 6] = mx;
  __syncthreads();
  mx = fmaxf(fmaxf(red[0], red[1]), fmaxf(red[2], red[3]));
  float e0 = (t < PP) ? __expf(v0 - mx) : 0.f;
  float e1 = (t + 256 < PP) ? __expf(v1 - mx) : 0.f;
  float sm = e0 + e1;
  #pragma unroll
  for (int off = 32; off; off >>= 1) sm += __shfl_xor(sm, off);
  if ((t & 63) == 0) red[4 + (t >> 6)] = sm;
  __syncthreads();
  float inv = 1.f / (red[4] + red[5] + red[6] + red[7]);
  float p0 = e0 * inv, p1 = e1 * inv;
  if (t < PP)       kout[(size_t)(b * PP + t) * SS + s] = p0;
  if (t + 256 < PP) kout[(size_t)(b * PP + t + 256) * SS + s] = p1;

  int kr0 = t / KS, kc0 = t - kr0 * KS;
  int t1 = t + 256;
  int kr1 = t1 / KS, kc1 = t1 - kr1 * KS;
  int ih0 = h + kr0 - 10; ih0 = (ih0 < 0) ? -ih0 : (ih0 > 47 ? 94 - ih0 : ih0);
  int iw0 = w + kc0 - 10; iw0 = (iw0 < 0) ? -iw0 : (iw0 > 47 ? 94 - iw0 : iw0);
  int ih1 = h + kr1 - 10; ih1 = (ih1 < 0) ? -ih1 : (ih1 > 47 ? 94 - ih1 : ih1);
  int iw1 = w + kc1 - 10; iw1 = (iw1 < 0) ? -iw1 : (iw1 > 47 ? 94 - iw1 : iw1);
  float acc[3];
  #pragma unroll
  for (int c = 0; c < 3; ++c) {
    const float* xb = x + (size_t)(b * CC + c) * HH * WW;
    float a = 0.f;
    if (t < PP)  a = p0 * xb[ih0 * WW + iw0];
    if (t1 < PP) a = fmaf(p1, xb[ih1 * WW + iw1], a);
    acc[c] = a;
  }
  #pragma unroll
  for (int c = 0; c < 3; ++c) {
    #pragma unroll
    for (int off = 32; off; off >>= 1) acc[c] += __shfl_xor(acc[c], off);
  }
  if ((t & 63) == 0) {
    gred[0][t >> 6] = acc[0];
    gred[1][t >> 6] = acc[1];
    gred[2][t >> 6] = acc[2];
  }
  __syncthreads();
  if (t < 3) {
    float r = gred[t][0] + gred[t][1] + gred[t][2] + gred[t][3];
    out[((size_t)(b * CC + t) * HH + h) * WW + w] = r;
  }
}

extern "C" void kernel_launch(void* const* d_in, const int* in_sizes, int n_in,
                              void* d_out, int out_size, void* d_ws, size_t ws_size,
                              hipStream_t stream)
{
  (void)in_sizes; (void)n_in; (void)out_size; (void)ws_size;
  const float* x       = (const float*)d_in[0];
  const float* conv1_w = (const float*)d_in[1];
  const float* conv1_b = (const float*)d_in[2];
  const float* bn_g    = (const float*)d_in[3];
  const float* bn_b    = (const float*)d_in[4];
  const float* bn_m    = (const float*)d_in[5];
  const float* bn_v    = (const float*)d_in[6];
  const float* w_in    = (const float*)d_in[7];
  const float* b_in    = (const float*)d_in[8];
  const float* w_out   = (const float*)d_in[9];
  const float* b_out   = (const float*)d_in[10];
  const float* w1      = (const float*)d_in[11];
  const float* b1      = (const float*)d_in[12];
  const float* w2      = (const float*)d_in[13];
  const float* b2      = (const float*)d_in[14];
  const float* ln1g    = (const float*)d_in[15];
  const float* ln1b    = (const float*)d_in[16];
  const float* ln2g    = (const float*)d_in[17];
  const float* ln2b    = (const float*)d_in[18];
  const float* lw      = (const float*)d_in[19];
  const float* lb      = (const float*)d_in[20];

  // workspace: ~42.8 MiB
  float* yA   = (float*)d_ws;        // 294912 (layer y, even layers)
  float* qkv  = yA + 294912;         // 884736
  float* yB   = qkv + 884736;        // 294912 (layer y, odd layers)
  float* sc   = yB + 294912;         // union region: 4718592 floats
  float* pacc = sc;                  // attn acc partials: 4*16*2304*8 = 1179648
  float* pff  = sc;                  // FF partials: 16*4608*64 = 4718592
  float* pl   = sc + 4718592;        // attn l partials: 4*16*2304 = 147456
  ushort_t* yh  = (ushort_t*)(pl + 589824);
  ushort_t* yl  = (ushort_t*)(pl + 589824 + 147456);
  ushort_t* w1h = (ushort_t*)(pl + 589824 + 294912);
  ushort_t* w1l = (ushort_t*)(pl + 589824 + 294912 + 524288);
  ushort_t* w2h = (ushort_t*)(pl + 589824 + 294912 + 1048576);
  ushort_t* w2l = (ushort_t*)(pl + 589824 + 294912 + 1572864);
  float* logits = pl + 589824 + 294912 + 2097152;   // 2032128 floats

  float* ybuf[2] = {yA, yB};

  float* out0 = (float*)d_out;
  float* kout = out0 + (size_t)BB * CC * HH * WW;

  k_split2<<<8192, 256, 0, stream>>>(w1, w2, w1h, w1l, w2h, w2l);
  k_conv<<<1152, 256, 0, stream>>>(x, conv1_w, conv1_b, bn_g, bn_b, bn_m, bn_v, yA);

  for (int l = 0; l < NLL; ++l) {
    float* ycur = ybuf[l & 1];
    if (l == 0)
      k_gemm32f<<<dim3(144, 3), 256, 0, stream>>>(yA, w_in, b_in, qkv, 192,
          nullptr, nullptr, nullptr, nullptr, yA);
    else
      // reads prev-layer y, writes LN2 output into ycur (different buffer -> no race)
      k_gemm32f<<<dim3(144, 3), 256, 0, stream>>>(ybuf[(l - 1) & 1],
          w_in + (size_t)l * 192 * 64, b_in + l * 192, qkv, 192,
          pff, b2 + (l - 1) * DD, ln2g + (l - 1) * 64, ln2b + (l - 1) * 64, ycur);
    k_attn<<<dim3(16, 36, KSPLIT), 256, 0, stream>>>(qkv, pl, pacc);
    k_oproj_ln<<<144, 256, 0, stream>>>(pl, pacc, w_out + (size_t)l * 64 * 64,
        b_out + l * 64, ycur, ln1g + l * 64, ln1b + l * 64, yh, yl);
    k_ff<<<dim3(FFSPLIT, 72), 256, 0, stream>>>(yh, yl,
        w1h + (size_t)l * FFF * DD, w1l + (size_t)l * FFF * DD, b1 + (size_t)l * FFF,
        w2h + (size_t)l * FFF * DD, w2l + (size_t)l * FFF * DD, pff);
  }

  // final logits GEMM fused with layer 7's FF-reduce + LN2 (writes dead buffer)
  k_gemm32f<<<dim3(144, 7), 256, 0, stream>>>(ybuf[7 & 1], lw, lb, logits, 441,
      pff, b2 + 7 * DD, ln2g + 7 * 64, ln2b + 7 * 64, ybuf[0]);
  k_softgather<<<NROW, 256, 0, stream>>>(logits, x, kout, out0);
}